// Round 5
// baseline (605.757 us; speedup 1.0000x reference)
//
#include <hip/hip_runtime.h>
#include <hip/hip_bf16.h>

#define NTOK   256
#define DMODEL 512
#define NHEAD  8
#define HD     64
#define HALF   32
#define FF     1536
#define RCFF   2048
#define VOCAB  32000
#define NLAYER 2
#define NSTEPS 4
#define EPSV   1e-6f
#define THR    0.99f

typedef __attribute__((ext_vector_type(8))) short bf16x8;
typedef __attribute__((ext_vector_type(4))) float f32x4;

// ---------------- embedding gather ----------------
__global__ void k_embed(const int* __restrict__ ids, const float* __restrict__ emb,
                        float* __restrict__ x) {
    int row = blockIdx.x;
    int id = ids[row];
    for (int d = threadIdx.x; d < DMODEL; d += blockDim.x)
        x[row * DMODEL + d] = emb[(size_t)id * DMODEL + d];
}

// ---------------- rmsnorm (one block per row) ----------------
__global__ __launch_bounds__(256) void k_rmsnorm(const float* __restrict__ in,
                                                 const float* __restrict__ w,
                                                 float* __restrict__ out) {
    int row = blockIdx.x;
    const float* xr = in + (size_t)row * DMODEL;
    float s = 0.f;
    for (int d = threadIdx.x; d < DMODEL; d += 256) { float v = xr[d]; s += v * v; }
    __shared__ float red[4];
    int lane = threadIdx.x & 63, wv = threadIdx.x >> 6;
    for (int o = 32; o > 0; o >>= 1) s += __shfl_xor(s, o);
    if (lane == 0) red[wv] = s;
    __syncthreads();
    float tot = red[0] + red[1] + red[2] + red[3];
    float scale = rsqrtf(tot * (1.f / DMODEL) + EPSV);
    for (int d = threadIdx.x; d < DMODEL; d += 256)
        out[(size_t)row * DMODEL + d] = xr[d] * scale * w[d];
}

// ---------------- direct f32 matmul: C = A[256xK] @ W[KxN] (+res, +gelu) ----------------
__global__ __launch_bounds__(256) void k_mm_direct(const float* __restrict__ A,
                                                   const float* __restrict__ W,
                                                   const float* __restrict__ res,
                                                   float* __restrict__ C,
                                                   int K, int N, int act) {
    __shared__ float As[16][68];
    __shared__ float Ws[16][68];
    const int bn = blockIdx.x * 64;
    const int bm = blockIdx.y * 64;
    const int tx = threadIdx.x & 15;
    const int ty = threadIdx.x >> 4;
    float acc[4][4] = {};
    for (int k0 = 0; k0 < K; k0 += 16) {
#pragma unroll
        for (int r = 0; r < 4; ++r) {
            int idx = threadIdx.x + r * 256;
            int m = idx >> 4, kk = idx & 15;
            As[kk][m] = A[(size_t)(bm + m) * K + k0 + kk];
            int n = idx & 63, kw = idx >> 6;
            Ws[kw][n] = W[(size_t)(k0 + kw) * N + bn + n];
        }
        __syncthreads();
#pragma unroll
        for (int kk = 0; kk < 16; ++kk) {
            float4 av = *(const float4*)&As[kk][ty * 4];
            float4 bv = *(const float4*)&Ws[kk][tx * 4];
            float a[4] = {av.x, av.y, av.z, av.w};
            float b[4] = {bv.x, bv.y, bv.z, bv.w};
#pragma unroll
            for (int i = 0; i < 4; ++i)
#pragma unroll
                for (int j = 0; j < 4; ++j)
                    acc[i][j] = fmaf(a[i], b[j], acc[i][j]);
        }
        __syncthreads();
    }
#pragma unroll
    for (int i = 0; i < 4; ++i) {
        int m = bm + ty * 4 + i;
#pragma unroll
        for (int j = 0; j < 4; ++j) {
            size_t idx = (size_t)m * N + bn + tx * 4 + j;
            float s = acc[i][j];
            if (res) s += res[idx];
            if (act == 1) {
                float xg = s;
                float inner = 0.79788456080286536f * (xg + 0.044715f * xg * xg * xg);
                s = 0.5f * xg * (1.f + tanhf(inner));
            }
            C[idx] = s;
        }
    }
}

// ---------------- fused gate/up: C = silu(A@Wg) * (A@Wu) ----------------
__global__ __launch_bounds__(256) void k_gateup(const float* __restrict__ A,
                                                const float* __restrict__ Wg,
                                                const float* __restrict__ Wu,
                                                float* __restrict__ C) {
    __shared__ float As[16][68];
    __shared__ float Gs[16][68];
    __shared__ float Us[16][68];
    const int bn = blockIdx.x * 64;
    const int bm = blockIdx.y * 64;
    const int tx = threadIdx.x & 15;
    const int ty = threadIdx.x >> 4;
    float ag[4][4] = {};
    float au[4][4] = {};
    for (int k0 = 0; k0 < DMODEL; k0 += 16) {
#pragma unroll
        for (int r = 0; r < 4; ++r) {
            int idx = threadIdx.x + r * 256;
            int m = idx >> 4, kk = idx & 15;
            As[kk][m] = A[(size_t)(bm + m) * DMODEL + k0 + kk];
            int n = idx & 63, kw = idx >> 6;
            Gs[kw][n] = Wg[(size_t)(k0 + kw) * FF + bn + n];
            Us[kw][n] = Wu[(size_t)(k0 + kw) * FF + bn + n];
        }
        __syncthreads();
#pragma unroll
        for (int kk = 0; kk < 16; ++kk) {
            float4 av = *(const float4*)&As[kk][ty * 4];
            float4 gv = *(const float4*)&Gs[kk][tx * 4];
            float4 uv = *(const float4*)&Us[kk][tx * 4];
            float a[4] = {av.x, av.y, av.z, av.w};
            float g[4] = {gv.x, gv.y, gv.z, gv.w};
            float u[4] = {uv.x, uv.y, uv.z, uv.w};
#pragma unroll
            for (int i = 0; i < 4; ++i)
#pragma unroll
                for (int j = 0; j < 4; ++j) {
                    ag[i][j] = fmaf(a[i], g[j], ag[i][j]);
                    au[i][j] = fmaf(a[i], u[j], au[i][j]);
                }
        }
        __syncthreads();
    }
#pragma unroll
    for (int i = 0; i < 4; ++i) {
        int m = bm + ty * 4 + i;
#pragma unroll
        for (int j = 0; j < 4; ++j) {
            float g = ag[i][j];
            float sig = 1.f / (1.f + expf(-g));
            C[(size_t)m * FF + bn + tx * 4 + j] = g * sig * au[i][j];
        }
    }
}

// ---------------- split-K matmul partial (for large-K matmuls) ----------------
__global__ __launch_bounds__(256) void k_mm_part(const float* __restrict__ A,
                                                 const float* __restrict__ W,
                                                 float* __restrict__ Cp,
                                                 int K, int N, int kc) {
    __shared__ float As[16][68];
    __shared__ float Ws[16][68];
    const int bn = blockIdx.x * 64;
    const int bm = blockIdx.y * 64;
    const int kz = blockIdx.z * kc;
    const int tx = threadIdx.x & 15;
    const int ty = threadIdx.x >> 4;
    float acc[4][4] = {};
    for (int k0 = kz; k0 < kz + kc; k0 += 16) {
#pragma unroll
        for (int r = 0; r < 4; ++r) {
            int idx = threadIdx.x + r * 256;
            int m = idx >> 4, kk = idx & 15;
            As[kk][m] = A[(size_t)(bm + m) * K + k0 + kk];
            int n = idx & 63, kw = idx >> 6;
            Ws[kw][n] = W[(size_t)(k0 + kw) * N + bn + n];
        }
        __syncthreads();
#pragma unroll
        for (int kk = 0; kk < 16; ++kk) {
            float4 av = *(const float4*)&As[kk][ty * 4];
            float4 bv = *(const float4*)&Ws[kk][tx * 4];
            float a[4] = {av.x, av.y, av.z, av.w};
            float b[4] = {bv.x, bv.y, bv.z, bv.w};
#pragma unroll
            for (int i = 0; i < 4; ++i)
#pragma unroll
                for (int j = 0; j < 4; ++j)
                    acc[i][j] = fmaf(a[i], b[j], acc[i][j]);
        }
        __syncthreads();
    }
    float* cp = Cp + (size_t)blockIdx.z * (size_t)(gridDim.y * 64) * N;
#pragma unroll
    for (int i = 0; i < 4; ++i) {
        int m = bm + ty * 4 + i;
#pragma unroll
        for (int j = 0; j < 4; ++j)
            cp[(size_t)m * N + bn + tx * 4 + j] = acc[i][j];
    }
}

// ---------------- split-K reduce (+residual) ----------------
__global__ void k_mm_finish(const float* __restrict__ Cp, const float* __restrict__ res,
                            float* __restrict__ C, int tot, int zstride, int nz, int act) {
    int i = blockIdx.x * 256 + threadIdx.x;
    if (i >= tot) return;
    float s = 0.f;
    for (int z = 0; z < nz; ++z) s += Cp[(size_t)z * zstride + i];
    if (res) s += res[i];
    if (act == 1) {
        float xg = s;
        float inner = 0.79788456080286536f * (xg + 0.044715f * xg * xg * xg);
        s = 0.5f * xg * (1.f + tanhf(inner));
    }
    C[i] = s;
}

// ---------------- RoPE in-place on q,k halves of qkv ----------------
__global__ void k_rope(float* __restrict__ qkv) {
    int pos = blockIdx.x;
    int t = threadIdx.x;          // 256 = 8 heads * 32 pairs
    int h = t >> 5, d = t & 31;
    float inv = powf(10000.f, -(float)d / 32.f);
    float ang = (float)pos * inv;
    float c = cosf(ang), s = sinf(ang);
    float* q = qkv + (size_t)pos * FF + h * HD;
    float x1 = q[d], x2 = q[d + HALF];
    q[d] = x1 * c - x2 * s;
    q[d + HALF] = x1 * s + x2 * c;
    float* k = q + DMODEL;
    x1 = k[d]; x2 = k[d + HALF];
    k[d] = x1 * c - x2 * s;
    k[d + HALF] = x1 * s + x2 * c;
}

// ---------------- attention: one block per (head, query) ----------------
__global__ __launch_bounds__(256) void k_attn(const float* __restrict__ qkv,
                                              float* __restrict__ out) {
    int h = blockIdx.x;
    int qi = blockIdx.y;
    int t = threadIdx.x;
    __shared__ float qs[HD];
    __shared__ float ps[NTOK];
    __shared__ float red[4];
    __shared__ float red2[4];
    __shared__ float os[4][HD];
    if (t < HD) qs[t] = qkv[(size_t)qi * FF + h * HD + t];
    __syncthreads();
    float sc = -1e30f;
    if (t <= qi) {
        const float* kr = qkv + (size_t)t * FF + DMODEL + h * HD;
        float s = 0.f;
        for (int d = 0; d < HD; ++d) s = fmaf(qs[d], kr[d], s);
        sc = s * 0.125f;
    }
    float m = sc;
    for (int o = 32; o > 0; o >>= 1) m = fmaxf(m, __shfl_xor(m, o));
    int lane = t & 63, wv = t >> 6;
    if (lane == 0) red[wv] = m;
    __syncthreads();
    m = fmaxf(fmaxf(red[0], red[1]), fmaxf(red[2], red[3]));
    float e = (t <= qi) ? expf(sc - m) : 0.f;
    ps[t] = e;
    float sum = e;
    for (int o = 32; o > 0; o >>= 1) sum += __shfl_xor(sum, o);
    if (lane == 0) red2[wv] = sum;
    __syncthreads();
    sum = red2[0] + red2[1] + red2[2] + red2[3];
    float inv = 1.f / sum;
    int d = t & 63, g = t >> 6;
    float acc = 0.f;
    for (int ki = g; ki <= qi; ki += 4)
        acc = fmaf(ps[ki], qkv[(size_t)ki * FF + 2 * DMODEL + h * HD + d], acc);
    os[g][d] = acc * inv;
    __syncthreads();
    if (t < HD)
        out[(size_t)qi * DMODEL + h * HD + t] = os[0][t] + os[1][t] + os[2][t] + os[3][t];
}

// ---------------- halt logits: sigmoid(h . w_halt + b) ----------------
__global__ __launch_bounds__(64) void k_halt(const float* __restrict__ H,
                                             const float* __restrict__ w,
                                             const float* __restrict__ bptr,
                                             float* __restrict__ halt) {
    int s = blockIdx.y, row = blockIdx.x;
    const float* h = H + ((size_t)s * NTOK + row) * DMODEL;
    float acc = 0.f;
    for (int d = threadIdx.x; d < DMODEL; d += 64) acc = fmaf(h[d], w[d], acc);
    for (int o = 32; o > 0; o >>= 1) acc += __shfl_xor(acc, o);
    if (threadIdx.x == 0)
        halt[s * NTOK + row] = 1.f / (1.f + expf(-(acc + bptr[0])));
}

// ---------------- ACT combine weights + ponder ----------------
__global__ void k_act(const float* __restrict__ halt, float* __restrict__ wts,
                      float* __restrict__ ponder_out, float* __restrict__ w_out) {
    int i = threadIdx.x;  // 256 tokens, single block
    float p[4];
#pragma unroll
    for (int s = 0; s < 4; ++s) p[s] = halt[s * NTOK + i];
    p[0] = 0.f;  // MIN_STEPS = 1
    float cum = 0.f, rem = 0.f, w[4];
    int nrun = 0;
#pragma unroll
    for (int s = 0; s < 4; ++s) {
        float prev = cum;
        cum += p[s];
        bool running = prev < THR;
        bool use_rem = running && ((cum >= THR) || (s == 3));
        float v = 0.f;
        if (running) {
            v = use_rem ? (1.f - prev) : p[s];
            if (use_rem) rem += (1.f - prev);
            nrun++;
        }
        w[s] = v;
    }
#pragma unroll
    for (int s = 0; s < 4; ++s) { wts[i * 4 + s] = w[s]; w_out[i * 4 + s] = w[s]; }
    ponder_out[i] = (float)nrun + rem;
}

// ---------------- A = sum_s w_s * H_s ; B = sum_s w_s * H_{s+1} (bf16 out) ----------------
__global__ void k_ab(const float* __restrict__ H, const float* __restrict__ wts,
                     __hip_bfloat16* __restrict__ A, __hip_bfloat16* __restrict__ Bm) {
    int i = blockIdx.x;
    float w0 = wts[i * 4 + 0], w1 = wts[i * 4 + 1], w2 = wts[i * 4 + 2], w3 = wts[i * 4 + 3];
    for (int d = threadIdx.x; d < DMODEL; d += 256) {
        size_t base = (size_t)i * DMODEL + d;
        float h0 = H[base], h1 = H[base + NTOK * DMODEL], h2 = H[base + 2 * NTOK * DMODEL];
        float h3 = H[base + 3 * (size_t)NTOK * DMODEL], h4 = H[base + 4 * (size_t)NTOK * DMODEL];
        A[base]  = __float2bfloat16(w0 * h0 + w1 * h1 + w2 * h2 + w3 * h3);
        Bm[base] = __float2bfloat16(w0 * h1 + w1 * h2 + w2 * h3 + w3 * h4);
    }
}

// ---------------- final logits via MFMA: out = A @ Wy + B @ Wd ----------------
// 8 waves/block; block owns 64 cols x 256 rows. Per 32-k iteration BOTH the
// weight tile (f32->bf16) AND the A/B activation slices (256x32 bf16 each) are
// staged into LDS with coalesced loads. Fragment reads are contiguous 1KB per
// wave (conflict-free). This removes the per-lane 1KB-strided global gathers
// that pinned rounds 2/4 at ~145us (L2 request/latency bound).
__global__ __launch_bounds__(512) void k_logits_mfma(const __hip_bfloat16* __restrict__ Abf,
                                                     const __hip_bfloat16* __restrict__ Bbf,
                                                     const float* __restrict__ Wy,
                                                     const float* __restrict__ Wd,
                                                     float* __restrict__ out) {
    __shared__ short Alds[256 * 32];   // [row][k] row-major, 16 KB
    __shared__ short Blds[256 * 32];   // 16 KB
    __shared__ short Wys[32 * 70];     // padded weight tile
    __shared__ short Wds[32 * 70];
    const int tid  = threadIdx.x;
    const int wave = tid >> 6;
    const int lane = tid & 63;
    const int wrow = (wave & 1) * 128;        // row half owned by this wave
    const int wcol = (wave >> 1) * 16;        // 16-col group within block's 64
    const int cl   = lane & 15;
    const int kg   = lane >> 4;
    const int col  = blockIdx.x * 64 + wcol + cl;

    // weight staging coords: 512 threads cover 32(k) x 64(n) f32 tile
    const int kr = tid >> 4;                  // 0..31
    const int c4 = (tid & 15) * 4;            // 0,4,..,60
    // A/B staging coords: chunk c = tid + i*512; row = c>>2, kp = c&3
    const int sr0 = tid >> 2;                 // rows 0..127   (i=0)
    const int skp = (tid & 3) * 8;            // k element offset

    f32x4 acc[8];
#pragma unroll
    for (int i = 0; i < 8; ++i) acc[i] = (f32x4){0.f, 0.f, 0.f, 0.f};

    const float* gy = Wy + (size_t)kr * VOCAB + blockIdx.x * 64 + c4;
    const float* gd = Wd + (size_t)kr * VOCAB + blockIdx.x * 64 + c4;

    float4 ry = *(const float4*)gy;
    float4 rd = *(const float4*)gd;
    bf16x8 ra0 = *(const bf16x8*)(Abf + (size_t)sr0 * DMODEL + skp);
    bf16x8 ra1 = *(const bf16x8*)(Abf + (size_t)(sr0 + 128) * DMODEL + skp);
    bf16x8 rb0 = *(const bf16x8*)(Bbf + (size_t)sr0 * DMODEL + skp);
    bf16x8 rb1 = *(const bf16x8*)(Bbf + (size_t)(sr0 + 128) * DMODEL + skp);

    for (int t = 0; t < 16; ++t) {
        __syncthreads();  // previous iteration's fragment reads complete
        {
            short2 a, b;
            a.x = (short)__hip_bfloat16_raw(__float2bfloat16(ry.x)).x;
            a.y = (short)__hip_bfloat16_raw(__float2bfloat16(ry.y)).x;
            b.x = (short)__hip_bfloat16_raw(__float2bfloat16(ry.z)).x;
            b.y = (short)__hip_bfloat16_raw(__float2bfloat16(ry.w)).x;
            *(short2*)&Wys[kr * 70 + c4]     = a;
            *(short2*)&Wys[kr * 70 + c4 + 2] = b;
            a.x = (short)__hip_bfloat16_raw(__float2bfloat16(rd.x)).x;
            a.y = (short)__hip_bfloat16_raw(__float2bfloat16(rd.y)).x;
            b.x = (short)__hip_bfloat16_raw(__float2bfloat16(rd.z)).x;
            b.y = (short)__hip_bfloat16_raw(__float2bfloat16(rd.w)).x;
            *(short2*)&Wds[kr * 70 + c4]     = a;
            *(short2*)&Wds[kr * 70 + c4 + 2] = b;
            *(bf16x8*)&Alds[sr0 * 32 + skp]         = ra0;
            *(bf16x8*)&Alds[(sr0 + 128) * 32 + skp] = ra1;
            *(bf16x8*)&Blds[sr0 * 32 + skp]         = rb0;
            *(bf16x8*)&Blds[(sr0 + 128) * 32 + skp] = rb1;
        }
        if (t < 15) {  // prefetch next 32-k tile
            const int kn = (t + 1) * 32;
            ry  = *(const float4*)(gy + (size_t)(t + 1) * 32 * VOCAB);
            rd  = *(const float4*)(gd + (size_t)(t + 1) * 32 * VOCAB);
            ra0 = *(const bf16x8*)(Abf + (size_t)sr0 * DMODEL + kn + skp);
            ra1 = *(const bf16x8*)(Abf + (size_t)(sr0 + 128) * DMODEL + kn + skp);
            rb0 = *(const bf16x8*)(Bbf + (size_t)sr0 * DMODEL + kn + skp);
            rb1 = *(const bf16x8*)(Bbf + (size_t)(sr0 + 128) * DMODEL + kn + skp);
        }
        __syncthreads();  // LDS tile visible
        bf16x8 wy, wd;
#pragma unroll
        for (int j = 0; j < 8; ++j) {
            wy[j] = Wys[(kg * 8 + j) * 70 + wcol + cl];
            wd[j] = Wds[(kg * 8 + j) * 70 + wcol + cl];
        }
#pragma unroll
        for (int mt = 0; mt < 8; ++mt) {
            const int row = wrow + mt * 16 + cl;
            const bf16x8 a = *(const bf16x8*)&Alds[row * 32 + kg * 8];
            const bf16x8 b = *(const bf16x8*)&Blds[row * 32 + kg * 8];
            acc[mt] = __builtin_amdgcn_mfma_f32_16x16x32_bf16(a, wy, acc[mt], 0, 0, 0);
            acc[mt] = __builtin_amdgcn_mfma_f32_16x16x32_bf16(b, wd, acc[mt], 0, 0, 0);
        }
    }
    // C/D layout: col = lane&15, row-in-tile = kg*4 + r
#pragma unroll
    for (int mt = 0; mt < 8; ++mt)
#pragma unroll
        for (int r = 0; r < 4; ++r)
            out[(size_t)(wrow + mt * 16 + kg * 4 + r) * VOCAB + col] = acc[mt][r];
}

extern "C" void kernel_launch(void* const* d_in, const int* in_sizes, int n_in,
                              void* d_out, int out_size, void* d_ws, size_t ws_size,
                              hipStream_t stream) {
    const int*   ids          = (const int*)d_in[0];
    const float* emb          = (const float*)d_in[1];
    const float* attn_norm_w  = (const float*)d_in[2];
    const float* mlp_norm_w   = (const float*)d_in[3];
    const float* wqkv         = (const float*)d_in[4];
    const float* wo           = (const float*)d_in[5];
    const float* w_gate       = (const float*)d_in[6];
    const float* w_up         = (const float*)d_in[7];
    const float* w_down       = (const float*)d_in[8];
    const float* final_norm_w = (const float*)d_in[9];
    const float* rc_norm_w    = (const float*)d_in[10];
    const float* rc_w1        = (const float*)d_in[11];
    const float* rc_w2        = (const float*)d_in[12];
    const float* w_y          = (const float*)d_in[13];
    const float* w_delta      = (const float*)d_in[14];
    const float* w_halt       = (const float*)d_in[15];
    const float* b_halt       = (const float*)d_in[16];
    float* out = (float*)d_out;

    float* ws = (float*)d_ws;
    float* x       = ws + 0;         // 131072
    float* xn      = ws + 131072;    // 131072
    float* qkv     = ws + 262144;    // 393216
    float* attnout = ws + 655360;    // 131072
    float* g       = ws + 786432;    // 393216
    float* t1      = ws + 1179648;   // 524288 (rc mlp intermediate)
    float* states  = ws + 1703936;   // 131072
    float* states2 = ws + 1835008;   // 131072
    float* H       = ws + 1966080;   // 655360 (5 slices of 131072)
    float* haltb   = ws + 2621440;   // 1024
    float* wts     = ws + 2622464;   // 1024
    __hip_bfloat16* Abf = (__hip_bfloat16*)(ws + 2623488);   // 131072 bf16
    __hip_bfloat16* Bbf = (__hip_bfloat16*)(ws + 2754560);   // 131072 bf16
    float* Cp      = ws + 2885632;   // 2097152 floats of split-K partials

    // ---------- backbone ----------
    k_embed<<<NTOK, 256, 0, stream>>>(ids, emb, x);
    for (int l = 0; l < NLAYER; ++l) {
        k_rmsnorm<<<NTOK, 256, 0, stream>>>(x, attn_norm_w + l * DMODEL, xn);
        k_mm_direct<<<dim3(FF / 64, NTOK / 64), 256, 0, stream>>>(
            xn, wqkv + (size_t)l * DMODEL * FF, nullptr, qkv, DMODEL, FF, 0);
        k_rope<<<NTOK, 256, 0, stream>>>(qkv);
        k_attn<<<dim3(NHEAD, NTOK), 256, 0, stream>>>(qkv, attnout);
        k_mm_direct<<<dim3(DMODEL / 64, NTOK / 64), 256, 0, stream>>>(
            attnout, wo + (size_t)l * DMODEL * DMODEL, x, x, DMODEL, DMODEL, 0);
        k_rmsnorm<<<NTOK, 256, 0, stream>>>(x, mlp_norm_w + l * DMODEL, xn);
        k_gateup<<<dim3(FF / 64, NTOK / 64), 256, 0, stream>>>(
            xn, w_gate + (size_t)l * DMODEL * FF, w_up + (size_t)l * DMODEL * FF, g);
        // down: K=1536, split 12
        k_mm_part<<<dim3(DMODEL / 64, NTOK / 64, 12), 256, 0, stream>>>(
            g, w_down + (size_t)l * FF * DMODEL, Cp, FF, DMODEL, FF / 12);
        k_mm_finish<<<(NTOK * DMODEL + 255) / 256, 256, 0, stream>>>(
            Cp, x, x, NTOK * DMODEL, NTOK * DMODEL, 12, 0);
    }
    k_rmsnorm<<<NTOK, 256, 0, stream>>>(x, final_norm_w, states);

    // ---------- refinement steps (halt path stays f32) ----------
    float* scur = states;
    float* snxt = states2;
    for (int s = 0; s < NSTEPS; ++s) {
        k_rmsnorm<<<NTOK, 256, 0, stream>>>(scur, rc_norm_w, H + (size_t)s * NTOK * DMODEL);
        k_mm_direct<<<dim3(RCFF / 64, NTOK / 64), 256, 0, stream>>>(
            H + (size_t)s * NTOK * DMODEL, rc_w1, nullptr, t1, DMODEL, RCFF, 1);  // gelu
        k_mm_part<<<dim3(DMODEL / 64, NTOK / 64, 16), 256, 0, stream>>>(
            t1, rc_w2, Cp, RCFF, DMODEL, RCFF / 16);
        k_mm_finish<<<(NTOK * DMODEL + 255) / 256, 256, 0, stream>>>(
            Cp, scur, snxt, NTOK * DMODEL, NTOK * DMODEL, 16, 0);
        float* tmp = scur; scur = snxt; snxt = tmp;
    }
    k_rmsnorm<<<NTOK, 256, 0, stream>>>(scur, rc_norm_w, H + (size_t)NSTEPS * NTOK * DMODEL);

    // ---------- halt, ACT weights, A/B combine (bf16) ----------
    k_halt<<<dim3(NTOK, NSTEPS), 64, 0, stream>>>(H, w_halt, b_halt, haltb);
    k_act<<<1, 256, 0, stream>>>(haltb, wts, out + (size_t)NTOK * VOCAB,
                                 out + (size_t)NTOK * VOCAB + NTOK);
    k_ab<<<NTOK, 256, 0, stream>>>(H, wts, Abf, Bbf);

    // ---------- final logits (MFMA bf16, LDS-staged weights + activations) ----------
    k_logits_mfma<<<VOCAB / 64, 512, 0, stream>>>(Abf, Bbf, w_y, w_delta, out);
}

// Round 6
// 382.340 us; speedup vs baseline: 1.5843x; 1.5843x over previous
//
#include <hip/hip_runtime.h>
#include <hip/hip_bf16.h>

#define NTOK   256
#define DMODEL 512
#define NHEAD  8
#define HD     64
#define HALF   32
#define FF     1536
#define RCFF   2048
#define VOCAB  32000
#define NLAYER 2
#define NSTEPS 4
#define EPSV   1e-6f
#define THR    0.99f

typedef __attribute__((ext_vector_type(8))) short bf16x8;
typedef __attribute__((ext_vector_type(4))) float f32x4;

// ---------------- embedding gather ----------------
__global__ void k_embed(const int* __restrict__ ids, const float* __restrict__ emb,
                        float* __restrict__ x) {
    int row = blockIdx.x;
    int id = ids[row];
    for (int d = threadIdx.x; d < DMODEL; d += blockDim.x)
        x[row * DMODEL + d] = emb[(size_t)id * DMODEL + d];
}

// ---------------- rmsnorm (one block per row) ----------------
__global__ __launch_bounds__(256) void k_rmsnorm(const float* __restrict__ in,
                                                 const float* __restrict__ w,
                                                 float* __restrict__ out) {
    int row = blockIdx.x;
    const float* xr = in + (size_t)row * DMODEL;
    float s = 0.f;
    for (int d = threadIdx.x; d < DMODEL; d += 256) { float v = xr[d]; s += v * v; }
    __shared__ float red[4];
    int lane = threadIdx.x & 63, wv = threadIdx.x >> 6;
    for (int o = 32; o > 0; o >>= 1) s += __shfl_xor(s, o);
    if (lane == 0) red[wv] = s;
    __syncthreads();
    float tot = red[0] + red[1] + red[2] + red[3];
    float scale = rsqrtf(tot * (1.f / DMODEL) + EPSV);
    for (int d = threadIdx.x; d < DMODEL; d += 256)
        out[(size_t)row * DMODEL + d] = xr[d] * scale * w[d];
}

// ---------------- split-K matmul partial ----------------
__global__ __launch_bounds__(256) void k_mm_part(const float* __restrict__ A,
                                                 const float* __restrict__ W,
                                                 float* __restrict__ Cp,
                                                 int K, int N, int kc) {
    __shared__ float As[16][68];
    __shared__ float Ws[16][68];
    const int bn = blockIdx.x * 64;
    const int bm = blockIdx.y * 64;
    const int kz = blockIdx.z * kc;
    const int tx = threadIdx.x & 15;
    const int ty = threadIdx.x >> 4;
    float acc[4][4] = {};
    for (int k0 = kz; k0 < kz + kc; k0 += 16) {
#pragma unroll
        for (int r = 0; r < 4; ++r) {
            int idx = threadIdx.x + r * 256;
            int m = idx >> 4, kk = idx & 15;
            As[kk][m] = A[(size_t)(bm + m) * K + k0 + kk];
            int n = idx & 63, kw = idx >> 6;
            Ws[kw][n] = W[(size_t)(k0 + kw) * N + bn + n];
        }
        __syncthreads();
#pragma unroll
        for (int kk = 0; kk < 16; ++kk) {
            float4 av = *(const float4*)&As[kk][ty * 4];
            float4 bv = *(const float4*)&Ws[kk][tx * 4];
            float a[4] = {av.x, av.y, av.z, av.w};
            float b[4] = {bv.x, bv.y, bv.z, bv.w};
#pragma unroll
            for (int i = 0; i < 4; ++i)
#pragma unroll
                for (int j = 0; j < 4; ++j)
                    acc[i][j] = fmaf(a[i], b[j], acc[i][j]);
        }
        __syncthreads();
    }
    float* cp = Cp + (size_t)blockIdx.z * (size_t)(gridDim.y * 64) * N;
#pragma unroll
    for (int i = 0; i < 4; ++i) {
        int m = bm + ty * 4 + i;
#pragma unroll
        for (int j = 0; j < 4; ++j)
            cp[(size_t)m * N + bn + tx * 4 + j] = acc[i][j];
    }
}

// ---------------- gate+up combined split-K partial (one launch) ----------------
// z = 0..7: z>>2 selects gate(0)/up(1); z&3 selects the 128-wide k chunk.
__global__ __launch_bounds__(256) void k_gu_part(const float* __restrict__ A,
                                                 const float* __restrict__ Wg,
                                                 const float* __restrict__ Wu,
                                                 float* __restrict__ GU) {
    __shared__ float As[16][68];
    __shared__ float Ws[16][68];
    const int bn = blockIdx.x * 64;
    const int bm = blockIdx.y * 64;
    const int z = blockIdx.z;
    const float* W = (z >> 2) ? Wu : Wg;
    const int kz = (z & 3) * 128;
    const int tx = threadIdx.x & 15;
    const int ty = threadIdx.x >> 4;
    float acc[4][4] = {};
    for (int k0 = kz; k0 < kz + 128; k0 += 16) {
#pragma unroll
        for (int r = 0; r < 4; ++r) {
            int idx = threadIdx.x + r * 256;
            int m = idx >> 4, kk = idx & 15;
            As[kk][m] = A[(size_t)(bm + m) * DMODEL + k0 + kk];
            int n = idx & 63, kw = idx >> 6;
            Ws[kw][n] = W[(size_t)(k0 + kw) * FF + bn + n];
        }
        __syncthreads();
#pragma unroll
        for (int kk = 0; kk < 16; ++kk) {
            float4 av = *(const float4*)&As[kk][ty * 4];
            float4 bv = *(const float4*)&Ws[kk][tx * 4];
            float a[4] = {av.x, av.y, av.z, av.w};
            float b[4] = {bv.x, bv.y, bv.z, bv.w};
#pragma unroll
            for (int i = 0; i < 4; ++i)
#pragma unroll
                for (int j = 0; j < 4; ++j)
                    acc[i][j] = fmaf(a[i], b[j], acc[i][j]);
        }
        __syncthreads();
    }
    float* cp = GU + (size_t)z * (NTOK * FF);
#pragma unroll
    for (int i = 0; i < 4; ++i) {
        int m = bm + ty * 4 + i;
#pragma unroll
        for (int j = 0; j < 4; ++j)
            cp[(size_t)m * FF + bn + tx * 4 + j] = acc[i][j];
    }
}

// ---------------- split-K elementwise reduce (+optional gelu) ----------------
__global__ void k_mm_finish(const float* __restrict__ Cp, const float* __restrict__ res,
                            float* __restrict__ C, int tot, int zstride, int nz, int act) {
    int i = blockIdx.x * 256 + threadIdx.x;
    if (i >= tot) return;
    float s = 0.f;
    for (int z = 0; z < nz; ++z) s += Cp[(size_t)z * zstride + i];
    if (res) s += res[i];
    if (act == 1) {  // gelu (tanh approx, jax default)
        float xg = s;
        float inner = 0.79788456080286536f * (xg + 0.044715f * xg * xg * xg);
        s = 0.5f * xg * (1.f + tanhf(inner));
    }
    C[i] = s;
}

// ---------------- reduce + silu(g)*u  (gate z=0..3, up z=4..7) ----------------
__global__ void k_finish_silumul(const float* __restrict__ GU, float* __restrict__ C) {
    int i = blockIdx.x * 256 + threadIdx.x;   // tot = 256*1536
    float g = 0.f, u = 0.f;
#pragma unroll
    for (int z = 0; z < 4; ++z) {
        g += GU[(size_t)z * (NTOK * FF) + i];
        u += GU[(size_t)(z + 4) * (NTOK * FF) + i];
    }
    float sig = 1.f / (1.f + expf(-g));
    C[i] = g * sig * u;
}

// ---------------- reduce + residual + dual write (raw, rmsnorm) ----------------
// For N=512 outputs. One block per row.
__global__ __launch_bounds__(256) void k_finish_norm(const float* __restrict__ Cp,
                                                     const float* __restrict__ res,
                                                     const float* __restrict__ normw,
                                                     float* __restrict__ out_raw,
                                                     float* __restrict__ out_norm,
                                                     int nz) {
    int row = blockIdx.x, t = threadIdx.x;
    int c0 = t, c1 = t + 256;
    size_t base = (size_t)row * DMODEL;
    float v0 = 0.f, v1 = 0.f;
    for (int z = 0; z < nz; ++z) {
        size_t zb = (size_t)z * (NTOK * DMODEL) + base;
        v0 += Cp[zb + c0];
        v1 += Cp[zb + c1];
    }
    v0 += res[base + c0];
    v1 += res[base + c1];
    float ss = v0 * v0 + v1 * v1;
    __shared__ float red[4];
    int lane = t & 63, wv = t >> 6;
    for (int o = 32; o > 0; o >>= 1) ss += __shfl_xor(ss, o);
    if (lane == 0) red[wv] = ss;
    __syncthreads();
    float tot = red[0] + red[1] + red[2] + red[3];
    float scale = rsqrtf(tot * (1.f / DMODEL) + EPSV);
    out_raw[base + c0] = v0;
    out_raw[base + c1] = v1;
    out_norm[base + c0] = v0 * scale * normw[c0];
    out_norm[base + c1] = v1 * scale * normw[c1];
}

// ---------------- qkv reduce + RoPE fused (z=4 slices, N=1536) ----------------
__global__ __launch_bounds__(256) void k_qkv_finish_rope(const float* __restrict__ Cp,
                                                         float* __restrict__ qkv) {
    int pos = blockIdx.x, t = threadIdx.x;
    int h = t >> 5, d = t & 31;
    size_t base = (size_t)pos * FF;
    auto S = [&](int col) {
        float s = 0.f;
#pragma unroll
        for (int z = 0; z < 4; ++z) s += Cp[(size_t)z * (NTOK * FF) + base + col];
        return s;
    };
    int cq0 = h * HD + d, cq1 = cq0 + HALF;
    int ck0 = DMODEL + cq0, ck1 = ck0 + HALF;
    int cv0 = 2 * DMODEL + t, cv1 = cv0 + 256;
    float q0 = S(cq0), q1 = S(cq1);
    float k0 = S(ck0), k1 = S(ck1);
    float v0 = S(cv0), v1 = S(cv1);
    float inv = powf(10000.f, -(float)d / 32.f);
    float ang = (float)pos * inv;
    float c = cosf(ang), s = sinf(ang);
    qkv[base + cq0] = q0 * c - q1 * s;
    qkv[base + cq1] = q0 * s + q1 * c;
    qkv[base + ck0] = k0 * c - k1 * s;
    qkv[base + ck1] = k0 * s + k1 * c;
    qkv[base + cv0] = v0;
    qkv[base + cv1] = v1;
}

// ---------------- attention: one block per (head, query) ----------------
__global__ __launch_bounds__(256) void k_attn(const float* __restrict__ qkv,
                                              float* __restrict__ out) {
    int h = blockIdx.x;
    int qi = blockIdx.y;
    int t = threadIdx.x;
    __shared__ float qs[HD];
    __shared__ float ps[NTOK];
    __shared__ float red[4];
    __shared__ float red2[4];
    __shared__ float os[4][HD];
    if (t < HD) qs[t] = qkv[(size_t)qi * FF + h * HD + t];
    __syncthreads();
    float sc = -1e30f;
    if (t <= qi) {
        const float* kr = qkv + (size_t)t * FF + DMODEL + h * HD;
        float s = 0.f;
        for (int d = 0; d < HD; ++d) s = fmaf(qs[d], kr[d], s);
        sc = s * 0.125f;
    }
    float m = sc;
    for (int o = 32; o > 0; o >>= 1) m = fmaxf(m, __shfl_xor(m, o));
    int lane = t & 63, wv = t >> 6;
    if (lane == 0) red[wv] = m;
    __syncthreads();
    m = fmaxf(fmaxf(red[0], red[1]), fmaxf(red[2], red[3]));
    float e = (t <= qi) ? expf(sc - m) : 0.f;
    ps[t] = e;
    float sum = e;
    for (int o = 32; o > 0; o >>= 1) sum += __shfl_xor(sum, o);
    if (lane == 0) red2[wv] = sum;
    __syncthreads();
    sum = red2[0] + red2[1] + red2[2] + red2[3];
    float inv = 1.f / sum;
    int d = t & 63, g = t >> 6;
    float acc = 0.f;
    for (int ki = g; ki <= qi; ki += 4)
        acc = fmaf(ps[ki], qkv[(size_t)ki * FF + 2 * DMODEL + h * HD + d], acc);
    os[g][d] = acc * inv;
    __syncthreads();
    if (t < HD)
        out[(size_t)qi * DMODEL + h * HD + t] = os[0][t] + os[1][t] + os[2][t] + os[3][t];
}

// ---------------- halt dots + ACT combine + A/B build, one block per token ----
__global__ __launch_bounds__(256) void k_haltactab(const float* __restrict__ H,
                                                   const float* __restrict__ wh,
                                                   const float* __restrict__ bptr,
                                                   float* __restrict__ ponder_out,
                                                   float* __restrict__ w_out,
                                                   __hip_bfloat16* __restrict__ A,
                                                   __hip_bfloat16* __restrict__ Bm) {
    int i = blockIdx.x, t = threadIdx.x;
    int lane = t & 63, wv = t >> 6;
    __shared__ float red[4];
    __shared__ float hvals[3];
    __shared__ float hw[4];
    // halt dots for steps s=1..3 (p[0] is forced to 0 by MIN_STEPS)
    for (int s = 1; s <= 3; ++s) {
        const float* hr = H + ((size_t)s * NTOK + i) * DMODEL;
        float a = hr[t] * wh[t] + hr[t + 256] * wh[t + 256];
        for (int o = 32; o > 0; o >>= 1) a += __shfl_xor(a, o);
        if (lane == 0) red[wv] = a;
        __syncthreads();
        if (t == 0)
            hvals[s - 1] = 1.f / (1.f + expf(-(red[0] + red[1] + red[2] + red[3] + bptr[0])));
        __syncthreads();
    }
    if (t == 0) {
        float p[4] = {0.f, hvals[0], hvals[1], hvals[2]};
        float cum = 0.f, rem = 0.f;
        int nrun = 0;
#pragma unroll
        for (int s = 0; s < 4; ++s) {
            float prev = cum;
            cum += p[s];
            bool running = prev < THR;
            bool use_rem = running && ((cum >= THR) || (s == 3));
            float v = 0.f;
            if (running) {
                v = use_rem ? (1.f - prev) : p[s];
                if (use_rem) rem += (1.f - prev);
                nrun++;
            }
            hw[s] = v;
            w_out[i * 4 + s] = v;
        }
        ponder_out[i] = (float)nrun + rem;
    }
    __syncthreads();
    float w0 = hw[0], w1 = hw[1], w2 = hw[2], w3 = hw[3];
    size_t base = (size_t)i * DMODEL;
#pragma unroll
    for (int r = 0; r < 2; ++r) {
        int d = t + r * 256;
        float h0 = H[base + d];
        float h1 = H[(size_t)(NTOK * DMODEL) + base + d];
        float h2 = H[(size_t)(2 * NTOK * DMODEL) + base + d];
        float h3 = H[(size_t)(3 * NTOK * DMODEL) + base + d];
        float h4 = H[(size_t)(4 * NTOK * DMODEL) + base + d];
        A[base + d]  = __float2bfloat16(w0 * h0 + w1 * h1 + w2 * h2 + w3 * h3);
        Bm[base + d] = __float2bfloat16(w0 * h1 + w1 * h2 + w2 * h3 + w3 * h4);
    }
}

// ---------------- final logits via MFMA (verbatim from round 5, passing) -------
__global__ __launch_bounds__(512) void k_logits_mfma(const __hip_bfloat16* __restrict__ Abf,
                                                     const __hip_bfloat16* __restrict__ Bbf,
                                                     const float* __restrict__ Wy,
                                                     const float* __restrict__ Wd,
                                                     float* __restrict__ out) {
    __shared__ short Alds[256 * 32];
    __shared__ short Blds[256 * 32];
    __shared__ short Wys[32 * 70];
    __shared__ short Wds[32 * 70];
    const int tid  = threadIdx.x;
    const int wave = tid >> 6;
    const int lane = tid & 63;
    const int wrow = (wave & 1) * 128;
    const int wcol = (wave >> 1) * 16;
    const int cl   = lane & 15;
    const int kg   = lane >> 4;
    const int col  = blockIdx.x * 64 + wcol + cl;

    const int kr = tid >> 4;
    const int c4 = (tid & 15) * 4;
    const int sr0 = tid >> 2;
    const int skp = (tid & 3) * 8;

    f32x4 acc[8];
#pragma unroll
    for (int i = 0; i < 8; ++i) acc[i] = (f32x4){0.f, 0.f, 0.f, 0.f};

    const float* gy = Wy + (size_t)kr * VOCAB + blockIdx.x * 64 + c4;
    const float* gd = Wd + (size_t)kr * VOCAB + blockIdx.x * 64 + c4;

    float4 ry = *(const float4*)gy;
    float4 rd = *(const float4*)gd;
    bf16x8 ra0 = *(const bf16x8*)(Abf + (size_t)sr0 * DMODEL + skp);
    bf16x8 ra1 = *(const bf16x8*)(Abf + (size_t)(sr0 + 128) * DMODEL + skp);
    bf16x8 rb0 = *(const bf16x8*)(Bbf + (size_t)sr0 * DMODEL + skp);
    bf16x8 rb1 = *(const bf16x8*)(Bbf + (size_t)(sr0 + 128) * DMODEL + skp);

    for (int t = 0; t < 16; ++t) {
        __syncthreads();
        {
            short2 a, b;
            a.x = (short)__hip_bfloat16_raw(__float2bfloat16(ry.x)).x;
            a.y = (short)__hip_bfloat16_raw(__float2bfloat16(ry.y)).x;
            b.x = (short)__hip_bfloat16_raw(__float2bfloat16(ry.z)).x;
            b.y = (short)__hip_bfloat16_raw(__float2bfloat16(ry.w)).x;
            *(short2*)&Wys[kr * 70 + c4]     = a;
            *(short2*)&Wys[kr * 70 + c4 + 2] = b;
            a.x = (short)__hip_bfloat16_raw(__float2bfloat16(rd.x)).x;
            a.y = (short)__hip_bfloat16_raw(__float2bfloat16(rd.y)).x;
            b.x = (short)__hip_bfloat16_raw(__float2bfloat16(rd.z)).x;
            b.y = (short)__hip_bfloat16_raw(__float2bfloat16(rd.w)).x;
            *(short2*)&Wds[kr * 70 + c4]     = a;
            *(short2*)&Wds[kr * 70 + c4 + 2] = b;
            *(bf16x8*)&Alds[sr0 * 32 + skp]         = ra0;
            *(bf16x8*)&Alds[(sr0 + 128) * 32 + skp] = ra1;
            *(bf16x8*)&Blds[sr0 * 32 + skp]         = rb0;
            *(bf16x8*)&Blds[(sr0 + 128) * 32 + skp] = rb1;
        }
        if (t < 15) {
            const int kn = (t + 1) * 32;
            ry  = *(const float4*)(gy + (size_t)(t + 1) * 32 * VOCAB);
            rd  = *(const float4*)(gd + (size_t)(t + 1) * 32 * VOCAB);
            ra0 = *(const bf16x8*)(Abf + (size_t)sr0 * DMODEL + kn + skp);
            ra1 = *(const bf16x8*)(Abf + (size_t)(sr0 + 128) * DMODEL + kn + skp);
            rb0 = *(const bf16x8*)(Bbf + (size_t)sr0 * DMODEL + kn + skp);
            rb1 = *(const bf16x8*)(Bbf + (size_t)(sr0 + 128) * DMODEL + kn + skp);
        }
        __syncthreads();
        bf16x8 wy, wd;
#pragma unroll
        for (int j = 0; j < 8; ++j) {
            wy[j] = Wys[(kg * 8 + j) * 70 + wcol + cl];
            wd[j] = Wds[(kg * 8 + j) * 70 + wcol + cl];
        }
#pragma unroll
        for (int mt = 0; mt < 8; ++mt) {
            const int row = wrow + mt * 16 + cl;
            const bf16x8 a = *(const bf16x8*)&Alds[row * 32 + kg * 8];
            const bf16x8 b = *(const bf16x8*)&Blds[row * 32 + kg * 8];
            acc[mt] = __builtin_amdgcn_mfma_f32_16x16x32_bf16(a, wy, acc[mt], 0, 0, 0);
            acc[mt] = __builtin_amdgcn_mfma_f32_16x16x32_bf16(b, wd, acc[mt], 0, 0, 0);
        }
    }
#pragma unroll
    for (int mt = 0; mt < 8; ++mt)
#pragma unroll
        for (int r = 0; r < 4; ++r)
            out[(size_t)(wrow + mt * 16 + kg * 4 + r) * VOCAB + col] = acc[mt][r];
}

extern "C" void kernel_launch(void* const* d_in, const int* in_sizes, int n_in,
                              void* d_out, int out_size, void* d_ws, size_t ws_size,
                              hipStream_t stream) {
    const int*   ids          = (const int*)d_in[0];
    const float* emb          = (const float*)d_in[1];
    const float* attn_norm_w  = (const float*)d_in[2];
    const float* mlp_norm_w   = (const float*)d_in[3];
    const float* wqkv         = (const float*)d_in[4];
    const float* wo           = (const float*)d_in[5];
    const float* w_gate       = (const float*)d_in[6];
    const float* w_up         = (const float*)d_in[7];
    const float* w_down       = (const float*)d_in[8];
    const float* final_norm_w = (const float*)d_in[9];
    const float* rc_norm_w    = (const float*)d_in[10];
    const float* rc_w1        = (const float*)d_in[11];
    const float* rc_w2        = (const float*)d_in[12];
    const float* w_y          = (const float*)d_in[13];
    const float* w_delta      = (const float*)d_in[14];
    const float* w_halt       = (const float*)d_in[15];
    const float* b_halt       = (const float*)d_in[16];
    float* out = (float*)d_out;

    float* ws = (float*)d_ws;
    float* x       = ws + 0;         // 131072
    float* xn      = ws + 131072;    // 131072
    float* qkv     = ws + 262144;    // 393216
    float* attnout = ws + 655360;    // 131072
    float* g       = ws + 786432;    // 393216
    float* t1      = ws + 1179648;   // 524288  (refinement intermediate)
    float* states  = ws + 1703936;   // 131072
    float* states2 = ws + 1835008;   // 131072
    float* H       = ws + 1966080;   // 655360  (5 slices of 131072)
    __hip_bfloat16* Abf = (__hip_bfloat16*)(ws + 2623488);   // 131072 bf16
    __hip_bfloat16* Bbf = (__hip_bfloat16*)(ws + 2754560);   // 131072 bf16
    float* Cp      = ws + 2885632;   // 2097152 floats (split-K partials)
    // gate/up partials: 8 x 393216 floats; lives only between gu_part and
    // gu_finish, overlapping refinement-only regions (t1..H) and part of Cp
    // (temporally disjoint: wo's Cp consumed before gu_part, down's Cp written
    // after gu_finish).
    float* GU      = ws + 1179648;

    // ---------- backbone ----------
    k_embed<<<NTOK, 256, 0, stream>>>(ids, emb, x);
    k_rmsnorm<<<NTOK, 256, 0, stream>>>(x, attn_norm_w, xn);
    for (int l = 0; l < NLAYER; ++l) {
        // qkv: K=512 N=1536, split 4
        k_mm_part<<<dim3(FF / 64, 4, 4), 256, 0, stream>>>(
            xn, wqkv + (size_t)l * DMODEL * FF, Cp, DMODEL, FF, 128);
        k_qkv_finish_rope<<<NTOK, 256, 0, stream>>>(Cp, qkv);
        k_attn<<<dim3(NHEAD, NTOK), 256, 0, stream>>>(qkv, attnout);
        // wo: K=512 N=512, split 8; finish fused with rmsnorm(mlp_norm)
        k_mm_part<<<dim3(DMODEL / 64, 4, 8), 256, 0, stream>>>(
            attnout, wo + (size_t)l * DMODEL * DMODEL, Cp, DMODEL, DMODEL, 64);
        k_finish_norm<<<NTOK, 256, 0, stream>>>(Cp, x, mlp_norm_w + l * DMODEL, x, xn, 8);
        // gate+up: one launch, z=8
        k_gu_part<<<dim3(FF / 64, 4, 8), 256, 0, stream>>>(
            xn, w_gate + (size_t)l * DMODEL * FF, w_up + (size_t)l * DMODEL * FF, GU);
        k_finish_silumul<<<NTOK * FF / 256, 256, 0, stream>>>(GU, g);
        // down: K=1536 N=512, split 12; finish fused with next norm
        k_mm_part<<<dim3(DMODEL / 64, 4, 12), 256, 0, stream>>>(
            g, w_down + (size_t)l * FF * DMODEL, Cp, FF, DMODEL, 128);
        const float* nw = (l == 0) ? (attn_norm_w + DMODEL) : final_norm_w;
        float* nout = (l == 0) ? xn : states;
        k_finish_norm<<<NTOK, 256, 0, stream>>>(Cp, x, nw, x, nout, 12);
    }

    // ---------- refinement steps (halt path stays f32) ----------
    k_rmsnorm<<<NTOK, 256, 0, stream>>>(states, rc_norm_w, H);
    float* scur = states;
    float* snxt = states2;
    for (int s = 0; s < NSTEPS; ++s) {
        // w1: K=512 N=2048, split 4; gelu in finish
        k_mm_part<<<dim3(RCFF / 64, 4, 4), 256, 0, stream>>>(
            H + (size_t)s * NTOK * DMODEL, rc_w1, Cp, DMODEL, RCFF, 128);
        k_mm_finish<<<NTOK * RCFF / 256, 256, 0, stream>>>(
            Cp, nullptr, t1, NTOK * RCFF, NTOK * RCFF, 4, 1);
        // w2: K=2048 N=512, split 16; finish fused with residual + rmsnorm -> H_{s+1}
        k_mm_part<<<dim3(DMODEL / 64, 4, 16), 256, 0, stream>>>(
            t1, rc_w2, Cp, RCFF, DMODEL, 128);
        k_finish_norm<<<NTOK, 256, 0, stream>>>(
            Cp, scur, rc_norm_w, snxt, H + (size_t)(s + 1) * NTOK * DMODEL, 16);
        float* tmp = scur; scur = snxt; snxt = tmp;
    }

    // ---------- halt + ACT + A/B in one kernel ----------
    k_haltactab<<<NTOK, 256, 0, stream>>>(H, w_halt, b_halt,
                                          out + (size_t)NTOK * VOCAB,
                                          out + (size_t)NTOK * VOCAB + NTOK,
                                          Abf, Bbf);

    // ---------- final logits (MFMA bf16, LDS-staged weights + activations) ----
    k_logits_mfma<<<VOCAB / 64, 512, 0, stream>>>(Abf, Bbf, w_y, w_delta, out);
}